// Round 10
// baseline (154.233 us; speedup 1.0000x reference)
//
#include <hip/hip_runtime.h>
#include <cstdint>

// Problem constants: B=32, T=D=256, rows R = B*T = 8192, K = 256.
#define R_TOT 8192
#define KD    256
#define SLOT  ((size_t)R_TOT * KD)            // bytes per fp8 image (2,097,152)
// ws layout (bytes):  total ~4.8 MB
#define IVN_OFF  0                            // 64 f32: 1/frobenius-norm [ten][j]
#define ICN_OFF  256                          // 2*8192 f32: 1/col-norm [ten][j][s]
#define CSQ_OFF  (ICN_OFF + 65536)            // 8 tc-partials x 2*8192 f32 = 512 KB
#define MATS_OFF (CSQ_OFF + 524288)           // 2 fp8 images (Vq, Aq), swizzled, 4 MB

typedef float f32x4 __attribute__((ext_vector_type(4)));
typedef int   i32x4 __attribute__((ext_vector_type(4)));
typedef int   i32x8 __attribute__((ext_vector_type(8)));   // 32 fp8 = one MX MFMA operand

__device__ __forceinline__ void glds16(const void* g, void* l){
  __builtin_amdgcn_global_load_lds((const __attribute__((address_space(1))) uint32_t*)g,
                                   (__attribute__((address_space(3))) uint32_t*)l, 16, 0, 0);
}

// Image layout (R11-verbatim): plain k-order rows (256 B per image row r), 16B
// chunk c (k in [c*16, c*16+16)) stored at 16B slot c ^ (r & 15). XOR swizzle
// keeps MFMA-layout ds_read_b128 conflict-free (verified R7-R11).
__global__ void cast_ns_k(const float* __restrict__ V, const float* __restrict__ A,
                          unsigned char* __restrict__ mats, float* __restrict__ csq){
  const int tc = blockIdx.x, j = blockIdx.y, ten = blockIdx.z;
  const int tid = threadIdx.x;
  const int g    = tid & 31;                 // d-chunk of 8 floats = 8 fp8 bytes
  const int tsub = tid >> 5;                 // 0..7
  const int c    = g >> 1;                   // 16B chunk index 0..15
  const int half = g & 1;                    // which 8B half of the chunk
  const float* X = (ten ? A : V) + (size_t)j * 65536;
  unsigned char* M = mats + (size_t)ten * SLOT + (size_t)j * 65536;
  float cs[8];
  #pragma unroll
  for (int e = 0; e < 8; ++e) cs[e] = 0.f;
  #pragma unroll
  for (int tt = 0; tt < 4; ++tt){
    const int t = tc * 32 + tt * 8 + tsub;
    const float4 p0 = *(const float4*)(X + t * 256 + g * 8);
    const float4 p1 = *(const float4*)(X + t * 256 + g * 8 + 4);
    cs[0] += p0.x * p0.x; cs[1] += p0.y * p0.y; cs[2] += p0.z * p0.z; cs[3] += p0.w * p0.w;
    cs[4] += p1.x * p1.x; cs[5] += p1.y * p1.y; cs[6] += p1.z * p1.z; cs[7] += p1.w * p1.w;
    int d0 = __builtin_amdgcn_cvt_pk_fp8_f32(p0.x, p0.y, 0, false);
    d0     = __builtin_amdgcn_cvt_pk_fp8_f32(p0.z, p0.w, d0, true);
    int d1 = __builtin_amdgcn_cvt_pk_fp8_f32(p1.x, p1.y, 0, false);
    d1     = __builtin_amdgcn_cvt_pk_fp8_f32(p1.z, p1.w, d1, true);
    int2 o; o.x = d0; o.y = d1;
    *(int2*)(M + (size_t)t * 256 + (((c ^ (t & 15)) << 4) | (half << 3))) = o;
  }
  __shared__ float red[8][256];
  #pragma unroll
  for (int e = 0; e < 8; ++e) red[tsub][g * 8 + e] = cs[e];
  __syncthreads();
  float s = 0.f;
  #pragma unroll
  for (int gg = 0; gg < 8; ++gg) s += red[gg][tid];
  csq[(size_t)((tc * 2 + ten) * 32 + j) * 256 + tid] = s;
}

// Finish norms: sum 8 tc-partials; icn = rsqrt, ivn = rsqrt of row-sum. Grid (32, 2).
__global__ void nreduce_k(const float* __restrict__ csq, float* __restrict__ ivn,
                          float* __restrict__ icn){
  const int j = blockIdx.x, ten = blockIdx.y, s = threadIdx.x;
  float c = 0.f;
  #pragma unroll
  for (int tc = 0; tc < 8; ++tc)
    c += csq[(size_t)((tc * 2 + ten) * 32 + j) * 256 + s];
  icn[ten * 8192 + j * 256 + s] = rsqrtf(c + 1e-18f);
  __shared__ float red[256];
  red[s] = c; __syncthreads();
  for (int off = 128; off > 0; off >>= 1){
    if (s < off) red[s] += red[s + off];
    __syncthreads();
  }
  if (s == 0) ivn[ten * 32 + j] = rsqrtf(red[0] + 1e-18f);
}

// v23 = v22 + TWO j-tiles per barrier interval (16 syncs instead of 31).
// v22 post-mortem: staged bytes fixed (127MB), TLP fixed (4/SIMD), yet
// ~830 cy/wave-step retire vs ~280 MFMA + ~230 VALU demand. The residual is
// the per-step serial chain barrier->ds_read->lgkm(120)->MFMA(280)->exp->
// vmcnt->barrier, run in 8-wave lockstep 31 times. v23 interval: read b(A);
// MFMA(A) (B's ds_reads issued under A's 280cy of MFMA -> B lgkm hidden);
// exp(A); MFMA(B); exp(B); counted vmcnt; ONE barrier. Halves barrier count
// and halves exposed lgkm per tile. DMA: 4 tiles in flight, 8-deep 4KB bufs
// (LDS 68KB, 2 blocks/CU = 136 <= 160); vmcnt ladder exact (2..2,1,0),
// never drains mid-loop. Reg peak ~ afr64+rA16+rB16+S16+acc16 ~ 125 under
// the 128 budget of (512,4). SPILL DETECTOR: WRITE_SIZE (clean = 8MB;
// ballooned -> fallback = dir-split 256-thr blocks at (256,3)).
__global__ __launch_bounds__(512, 4) void gemm_both_k(const unsigned char* __restrict__ mats,
                                                      const float* __restrict__ ivn,
                                                      const float* __restrict__ icn,
                                                      float* __restrict__ out){
  // [0,64K): 2 dirs x 8 bufs x 4KB staging; [64K,68K): csc[2][32][16] f32.
  // Epilogue ebuf f32[2][256][20] = 40960 B aliases the staging (post-loop).
  __shared__ __align__(16) char smem[69632];
  const int tid  = threadIdx.x;
  const int lane = tid & 63;
  const int w    = tid >> 6;            // 0..7
  const int dir  = w >> 2;              // waves 0-3 -> dir0; 4-7 -> dir1
  const int sub  = w & 3;               // row-64-group AND staging-chunk index
  const int lm   = lane & 15;
  const int kh   = lane >> 4;           // 0..3 (k-quad per K-half)
  const int s0   = blockIdx.x * 16;     // 16-col tile
  const int rb   = blockIdx.y;          // row-block == batch index i
  const int r0   = rb * 256;
  const int ib   = rb;                  // excluded diagonal j == i

  // dir0: rows Vq (scale 1/|V_i|F), cols Aq (scale 1/colnorm A); dir1 swapped.
  const unsigned char* rowmat = mats + (size_t)dir * SLOT;
  const unsigned char* colmat = mats + (size_t)(1 - dir) * SLOT;
  const float sivn = ivn[dir * 32 + ib] * 1.44269504088896340736f;  // * log2(e)

  char*  dbase = smem + dir * 32768;                  // this dir's 8 x 4KB bufs
  float* cscw  = (float*)(smem + 65536) + dir * 512;  // this dir's csc[32][16]
  const unsigned char* colbase = colmat + (size_t)s0 * 256;  // 4KB j-tile @ +j*65536
  const int lo16 = lane * 16;

  // Stage this wave's 1KB chunk of the dir's 4KB tile for col-tile x.
  auto issue = [&](int x){
    const int j = x + (x >= ib ? 1 : 0);
    glds16(colbase + (size_t)j * 65536 + sub * 1024 + lo16,
           dbase + ((x & 7) << 12) + sub * 1024 + lo16);
  };

  issue(0); issue(1); issue(2); issue(3);

  // Block-shared csc table (per dir): csc[j][col] = sivn * icn_col[j*256+s0+col].
  {
    const float* ib2 = icn + (size_t)(1 - dir) * 8192 + s0 + lm;
    #pragma unroll
    for (int jx = 0; jx < 2; ++jx){
      const int j = sub * 8 + jx * 4 + kh;
      cscw[j * 16 + lm] = sivn * ib2[j * 256];
    }
  }

  // A-fragments: this wave's 64 rows (group sub of the 256-row block);
  // K-half t, 16B unit u at slot (t*8 + kh*2 + u) ^ lm. 64 regs, invariant.
  i32x8 afr[4][2];                      // [mi][K-half]
  #pragma unroll
  for (int mi = 0; mi < 4; ++mi){
    const unsigned char* rp = rowmat + (size_t)(r0 + sub * 64 + mi * 16 + lm) * 256;
    #pragma unroll
    for (int t = 0; t < 2; ++t){
      i32x4 lo = *(const i32x4*)(rp + ((((t << 3) | (kh << 1) | 0) ^ lm) << 4));
      i32x4 hi = *(const i32x4*)(rp + ((((t << 3) | (kh << 1) | 1) ^ lm) << 4));
      afr[mi][t] = i32x8{lo.x, lo.y, lo.z, lo.w, hi.x, hi.y, hi.z, hi.w};
    }
  }
  #pragma unroll
  for (int mi = 0; mi < 4; ++mi)
    #pragma unroll
    for (int t = 0; t < 2; ++t)
      asm volatile("" : "+v"(afr[mi][t]));

  // ds_read offsets: tile row lm, K-half t, unit u; (row&15)==lm so the XOR
  // key matches staging (s0 multiple of 16).
  int ad[2][2];                         // [K-half][unit]
  #pragma unroll
  for (int t = 0; t < 2; ++t)
    #pragma unroll
    for (int u = 0; u < 2; ++u)
      ad[t][u] = lm * 256 + ((((t << 3) | (kh << 1) | u) ^ lm) << 4);

  f32x4 acc[4];
  #pragma unroll
  for (int mi = 0; mi < 4; ++mi)
    acc[mi] = f32x4{0.f, 0.f, 0.f, 0.f};
  const f32x4 fz = {0.f, 0.f, 0.f, 0.f};   // hoisted zero C-operand for MFMA t=0

  // Drain prologue (csc gloads + afr + DMA(0..3) + csc LDS writes), sync.
  asm volatile("s_waitcnt vmcnt(0) lgkmcnt(0)" ::: "memory");
  __builtin_amdgcn_s_barrier();
  __builtin_amdgcn_sched_barrier(0);

#define RD(RX, BUF) do{                                                         \
    i32x4 lo0_ = *(const i32x4*)((BUF) + ad[0][0]);                             \
    i32x4 hi0_ = *(const i32x4*)((BUF) + ad[0][1]);                             \
    i32x4 lo1_ = *(const i32x4*)((BUF) + ad[1][0]);                             \
    i32x4 hi1_ = *(const i32x4*)((BUF) + ad[1][1]);                             \
    RX[0] = i32x8{lo0_.x, lo0_.y, lo0_.z, lo0_.w, hi0_.x, hi0_.y, hi0_.z, hi0_.w}; \
    RX[1] = i32x8{lo1_.x, lo1_.y, lo1_.z, lo1_.w, hi1_.x, hi1_.y, hi1_.z, hi1_.w}; \
  }while(0)

#define MFMA8(SX, BX) do{                                                       \
    _Pragma("unroll")                                                           \
    for (int mi_ = 0; mi_ < 4; ++mi_)                                           \
      SX[mi_] = __builtin_amdgcn_mfma_scale_f32_16x16x128_f8f6f4(afr[mi_][0], BX[0], fz, 0, 0, 0, 127, 0, 127); \
    _Pragma("unroll")                                                           \
    for (int mi_ = 0; mi_ < 4; ++mi_)                                           \
      SX[mi_] = __builtin_amdgcn_mfma_scale_f32_16x16x128_f8f6f4(afr[mi_][1], BX[1], SX[mi_], 0, 0, 0, 127, 0, 127); \
  }while(0)

#define EXPACC(SX, CY) do{                                                      \
    _Pragma("unroll")                                                           \
    for (int mi_ = 0; mi_ < 4; ++mi_){                                          \
      const f32x4 t_ = SX[mi_] * (CY);                                          \
      f32x4 e_;                                                                 \
      _Pragma("unroll")                                                         \
      for (int r_ = 0; r_ < 4; ++r_) e_[r_] = __builtin_amdgcn_exp2f(t_[r_]);   \
      acc[mi_] += e_;                                                           \
    }                                                                           \
  }while(0)

// One interval: tiles xa_, xb_ (= xa_+1). NISS = how many of {xa_+4, xb_+4}
// to DMA. VN = vmcnt literal at interval end (waits tiles {xa_+2, xb_+2}).
// B's ds_reads sit under A's MFMA+exp (~400cy) -> B lgkm fully hidden; only
// A's ~120cy lgkm is exposed per 2 tiles. Compiler inserts exact lgkmcnt.
#define PAIR(xa_, xb_, NISS, VN) do{                                            \
    const int ja_ = (xa_) + ((xa_) >= ib ? 1 : 0);                              \
    const int jb_ = (xb_) + ((xb_) >= ib ? 1 : 0);                              \
    const char* bufa_ = dbase + (((xa_) & 7) << 12);                            \
    const char* bufb_ = dbase + (((xb_) & 7) << 12);                            \
    i32x8 rA_[2], rB_[2];                                                       \
    f32x4 S_[4];                                                                \
    RD(rA_, bufa_);                                                             \
    const float cA_ = cscw[ja_ * 16 + lm];                                      \
    if ((NISS) >= 1) issue((xa_) + 4);                                          \
    if ((NISS) >= 2) issue((xb_) + 4);                                          \
    MFMA8(S_, rA_);                                                             \
    RD(rB_, bufb_);                                                             \
    const float cB_ = cscw[jb_ * 16 + lm];                                      \
    EXPACC(S_, cA_);                                                            \
    MFMA8(S_, rB_);                                                             \
    EXPACC(S_, cB_);                                                            \
    asm volatile("s_waitcnt vmcnt(" #VN ")" ::: "memory");                      \
    __builtin_amdgcn_s_barrier();                                               \
    __builtin_amdgcn_sched_barrier(0);                                          \
  }while(0)

  // Intervals k=0..12: tiles (2k, 2k+1); issue (2k+4, 2k+5); vmcnt(2) waits
  // (2k+2, 2k+3) -- exactly what interval k+1 consumes.
  #pragma unroll 1
  for (int k = 0; k < 13; ++k)
    PAIR(2 * k, 2 * k + 1, 2, 2);
  // k=13: tiles (26,27); issue 30 only; vmcnt(1) waits (28,29).
  PAIR(26, 27, 1, 1);
  // k=14: tiles (28,29); no issue; vmcnt(0) waits 30.
  PAIR(28, 29, 0, 0);
  // Final single tile 30 (data landed; barrier passed).
  {
    const int j30 = 30 + (30 >= ib ? 1 : 0);
    const char* buf_ = dbase + ((30 & 7) << 12);
    i32x8 r_[2];
    f32x4 S_[4];
    RD(r_, buf_);
    const float c_ = cscw[j30 * 16 + lm];
    MFMA8(S_, r_);
    EXPACC(S_, c_);
  }

#undef PAIR
#undef EXPACC
#undef MFMA8
#undef RD

  // Epilogue: per-dir log1p into LDS (aliases staging -- dead now), combine
  // dirs, coalesced store. C/D layout: col = lane&15, row = (lane>>4)*4+reg.
  __syncthreads();
  float* ebuf = (float*)smem;
  #pragma unroll
  for (int mi = 0; mi < 4; ++mi){
    #pragma unroll
    for (int r = 0; r < 4; ++r){
      const int m = sub * 64 + mi * 16 + (kh << 2) + r;
      ebuf[(dir * 256 + m) * 20 + lm] = __logf(1.f + acc[mi][r]);
    }
  }
  __syncthreads();
  #pragma unroll
  for (int p = 0; p < 2; ++p){
    const int i   = tid + p * 512;     // 0..1023 (float4 units of the 256x16 tile)
    const int row = i >> 2;
    const int c4  = i & 3;
    const f32x4 e0 = *(const f32x4*)(&ebuf[row * 20 + c4 * 4]);
    const f32x4 e1 = *(const f32x4*)(&ebuf[(256 + row) * 20 + c4 * 4]);
    f32x4 o;
    #pragma unroll
    for (int e = 0; e < 4; ++e) o[e] = -(e0[e] + e1[e]);
    *(f32x4*)(&out[(size_t)(r0 + row) * 256 + s0 + c4 * 4]) = o;
  }
}

extern "C" void kernel_launch(void* const* d_in, const int* in_sizes, int n_in,
                              void* d_out, int out_size, void* d_ws, size_t ws_size,
                              hipStream_t stream){
  const float* V = (const float*)d_in[2];   // back_VF  (pre_VF/pre_AF unused by reference)
  const float* A = (const float*)d_in[3];   // back_AF
  float* out = (float*)d_out;
  float* ivn = (float*)((char*)d_ws + IVN_OFF);
  float* icn = (float*)((char*)d_ws + ICN_OFF);
  float* csq = (float*)((char*)d_ws + CSQ_OFF);
  unsigned char* mats = (unsigned char*)((char*)d_ws + MATS_OFF);

  cast_ns_k<<<dim3(8, 32, 2), 256, 0, stream>>>(V, A, mats, csq);
  nreduce_k<<<dim3(32, 2), 256, 0, stream>>>(csq, ivn, icn);
  gemm_both_k<<<dim3(16, 32), 512, 0, stream>>>(mats, ivn, icn, out);
}

// Round 11
// 118.452 us; speedup vs baseline: 1.3021x; 1.3021x over previous
//
#include <hip/hip_runtime.h>
#include <cstdint>

// Problem constants: B=32, T=D=256, rows R = B*T = 8192, K = 256.
#define R_TOT 8192
#define KD    256
#define SLOT  ((size_t)R_TOT * KD)            // bytes per fp8 image (2,097,152)
// ws layout (bytes):  total ~4.8 MB
#define IVN_OFF  0                            // 64 f32: 1/frobenius-norm [ten][j]
#define ICN_OFF  256                          // 2*8192 f32: 1/col-norm [ten][j][s]
#define CSQ_OFF  (ICN_OFF + 65536)            // 8 tc-partials x 2*8192 f32 = 512 KB
#define MATS_OFF (CSQ_OFF + 524288)           // 2 fp8 images (Vq, Aq), swizzled, 4 MB

typedef float f32x4 __attribute__((ext_vector_type(4)));
typedef int   i32x4 __attribute__((ext_vector_type(4)));
typedef int   i32x8 __attribute__((ext_vector_type(8)));   // 32 fp8 = one MX MFMA operand

__device__ __forceinline__ void glds16(const void* g, void* l){
  __builtin_amdgcn_global_load_lds((const __attribute__((address_space(1))) uint32_t*)g,
                                   (__attribute__((address_space(3))) uint32_t*)l, 16, 0, 0);
}

// Image layout (R11-verbatim): plain k-order rows (256 B per image row r), 16B
// chunk c (k in [c*16, c*16+16)) stored at 16B slot c ^ (r & 15). XOR swizzle
// keeps MFMA-layout ds_read_b128 conflict-free (verified R7-R11).
__global__ void cast_ns_k(const float* __restrict__ V, const float* __restrict__ A,
                          unsigned char* __restrict__ mats, float* __restrict__ csq){
  const int tc = blockIdx.x, j = blockIdx.y, ten = blockIdx.z;
  const int tid = threadIdx.x;
  const int g    = tid & 31;                 // d-chunk of 8 floats = 8 fp8 bytes
  const int tsub = tid >> 5;                 // 0..7
  const int c    = g >> 1;                   // 16B chunk index 0..15
  const int half = g & 1;                    // which 8B half of the chunk
  const float* X = (ten ? A : V) + (size_t)j * 65536;
  unsigned char* M = mats + (size_t)ten * SLOT + (size_t)j * 65536;
  float cs[8];
  #pragma unroll
  for (int e = 0; e < 8; ++e) cs[e] = 0.f;
  #pragma unroll
  for (int tt = 0; tt < 4; ++tt){
    const int t = tc * 32 + tt * 8 + tsub;
    const float4 p0 = *(const float4*)(X + t * 256 + g * 8);
    const float4 p1 = *(const float4*)(X + t * 256 + g * 8 + 4);
    cs[0] += p0.x * p0.x; cs[1] += p0.y * p0.y; cs[2] += p0.z * p0.z; cs[3] += p0.w * p0.w;
    cs[4] += p1.x * p1.x; cs[5] += p1.y * p1.y; cs[6] += p1.z * p1.z; cs[7] += p1.w * p1.w;
    int d0 = __builtin_amdgcn_cvt_pk_fp8_f32(p0.x, p0.y, 0, false);
    d0     = __builtin_amdgcn_cvt_pk_fp8_f32(p0.z, p0.w, d0, true);
    int d1 = __builtin_amdgcn_cvt_pk_fp8_f32(p1.x, p1.y, 0, false);
    d1     = __builtin_amdgcn_cvt_pk_fp8_f32(p1.z, p1.w, d1, true);
    int2 o; o.x = d0; o.y = d1;
    *(int2*)(M + (size_t)t * 256 + (((c ^ (t & 15)) << 4) | (half << 3))) = o;
  }
  __shared__ float red[8][256];
  #pragma unroll
  for (int e = 0; e < 8; ++e) red[tsub][g * 8 + e] = cs[e];
  __syncthreads();
  float s = 0.f;
  #pragma unroll
  for (int gg = 0; gg < 8; ++gg) s += red[gg][tid];
  csq[(size_t)((tc * 2 + ten) * 32 + j) * 256 + tid] = s;
}

// Finish norms: sum 8 tc-partials; icn = rsqrt, ivn = rsqrt of row-sum. Grid (32, 2).
__global__ void nreduce_k(const float* __restrict__ csq, float* __restrict__ ivn,
                          float* __restrict__ icn){
  const int j = blockIdx.x, ten = blockIdx.y, s = threadIdx.x;
  float c = 0.f;
  #pragma unroll
  for (int tc = 0; tc < 8; ++tc)
    c += csq[(size_t)((tc * 2 + ten) * 32 + j) * 256 + s];
  icn[ten * 8192 + j * 256 + s] = rsqrtf(c + 1e-18f);
  __shared__ float red[256];
  red[s] = c; __syncthreads();
  for (int off = 128; off > 0; off >>= 1){
    if (s < off) red[s] += red[s + off];
    __syncthreads();
  }
  if (s == 0) ivn[ten * 32 + j] = rsqrtf(red[0] + 1e-18f);
}

// v24 = v22 geometry + barrier-halving retested at v22's register budget.
// v23's pair-interval held rA+rB+S simultaneously (~160 live vs 128 budget
// at (512,4)) -> spill (WRITE 94MB, VGPR_Count squeezed to 64, 85us). v24
// keeps the two-tiles-per-barrier idea but SEQUENTIAL: one shared r/S
// buffer; tile B's ds_reads issue only after tile A's regs die, pinned by
// sched_barrier(0) so the compiler cannot hoist them into A's live range.
// Peak live = afr64 + r32 + S16 + acc16 ~= 128 = v22's proven-fit set.
// Hazards: own-DMA for tiles (2k,2k+1) confirmed by vmcnt(2) at end of
// interval k-1; cross-wave visibility by that barrier; WAR slack = 8-deep
// buffers / 2 tiles per interval = 4 intervals. Sync tax: 16 barriers + 16
// vmcnt waits (vs v22's 31+31). SPILL DETECTOR: WRITE_SIZE (clean = 8MB).
__global__ __launch_bounds__(512, 4) void gemm_both_k(const unsigned char* __restrict__ mats,
                                                      const float* __restrict__ ivn,
                                                      const float* __restrict__ icn,
                                                      float* __restrict__ out){
  // [0,64K): 2 dirs x 8 bufs x 4KB staging; [64K,68K): csc[2][32][16] f32.
  // Epilogue ebuf f32[2][256][20] = 40960 B aliases the staging (post-loop).
  __shared__ __align__(16) char smem[69632];
  const int tid  = threadIdx.x;
  const int lane = tid & 63;
  const int w    = tid >> 6;            // 0..7
  const int dir  = w >> 2;              // waves 0-3 -> dir0; 4-7 -> dir1
  const int sub  = w & 3;               // row-64-group AND staging-chunk index
  const int lm   = lane & 15;
  const int kh   = lane >> 4;           // 0..3 (k-quad per K-half)
  const int s0   = blockIdx.x * 16;     // 16-col tile
  const int rb   = blockIdx.y;          // row-block == batch index i
  const int r0   = rb * 256;
  const int ib   = rb;                  // excluded diagonal j == i

  // dir0: rows Vq (scale 1/|V_i|F), cols Aq (scale 1/colnorm A); dir1 swapped.
  const unsigned char* rowmat = mats + (size_t)dir * SLOT;
  const unsigned char* colmat = mats + (size_t)(1 - dir) * SLOT;
  const float sivn = ivn[dir * 32 + ib] * 1.44269504088896340736f;  // * log2(e)

  char*  dbase = smem + dir * 32768;                  // this dir's 8 x 4KB bufs
  float* cscw  = (float*)(smem + 65536) + dir * 512;  // this dir's csc[32][16]
  const unsigned char* colbase = colmat + (size_t)s0 * 256;  // 4KB j-tile @ +j*65536
  const int lo16 = lane * 16;

  // Stage this wave's 1KB chunk of the dir's 4KB tile for col-tile x.
  auto issue = [&](int x){
    const int j = x + (x >= ib ? 1 : 0);
    glds16(colbase + (size_t)j * 65536 + sub * 1024 + lo16,
           dbase + ((x & 7) << 12) + sub * 1024 + lo16);
  };

  issue(0); issue(1); issue(2); issue(3);

  // Block-shared csc table (per dir): csc[j][col] = sivn * icn_col[j*256+s0+col].
  {
    const float* ib2 = icn + (size_t)(1 - dir) * 8192 + s0 + lm;
    #pragma unroll
    for (int jx = 0; jx < 2; ++jx){
      const int j = sub * 8 + jx * 4 + kh;
      cscw[j * 16 + lm] = sivn * ib2[j * 256];
    }
  }

  // A-fragments: this wave's 64 rows (group sub of the 256-row block);
  // K-half t, 16B unit u at slot (t*8 + kh*2 + u) ^ lm. 64 regs, invariant.
  i32x8 afr[4][2];                      // [mi][K-half]
  #pragma unroll
  for (int mi = 0; mi < 4; ++mi){
    const unsigned char* rp = rowmat + (size_t)(r0 + sub * 64 + mi * 16 + lm) * 256;
    #pragma unroll
    for (int t = 0; t < 2; ++t){
      i32x4 lo = *(const i32x4*)(rp + ((((t << 3) | (kh << 1) | 0) ^ lm) << 4));
      i32x4 hi = *(const i32x4*)(rp + ((((t << 3) | (kh << 1) | 1) ^ lm) << 4));
      afr[mi][t] = i32x8{lo.x, lo.y, lo.z, lo.w, hi.x, hi.y, hi.z, hi.w};
    }
  }
  #pragma unroll
  for (int mi = 0; mi < 4; ++mi)
    #pragma unroll
    for (int t = 0; t < 2; ++t)
      asm volatile("" : "+v"(afr[mi][t]));

  // ds_read offsets: tile row lm, K-half t, unit u; (row&15)==lm so the XOR
  // key matches staging (s0 multiple of 16).
  int ad[2][2];                         // [K-half][unit]
  #pragma unroll
  for (int t = 0; t < 2; ++t)
    #pragma unroll
    for (int u = 0; u < 2; ++u)
      ad[t][u] = lm * 256 + ((((t << 3) | (kh << 1) | u) ^ lm) << 4);

  f32x4 acc[4];
  #pragma unroll
  for (int mi = 0; mi < 4; ++mi)
    acc[mi] = f32x4{0.f, 0.f, 0.f, 0.f};
  const f32x4 fz = {0.f, 0.f, 0.f, 0.f};   // hoisted zero C-operand for MFMA t=0

  // Drain prologue (csc gloads + afr + DMA(0..3) + csc LDS writes), sync.
  asm volatile("s_waitcnt vmcnt(0) lgkmcnt(0)" ::: "memory");
  __builtin_amdgcn_s_barrier();
  __builtin_amdgcn_sched_barrier(0);

#define RD(RX, BUF) do{                                                         \
    i32x4 lo0_ = *(const i32x4*)((BUF) + ad[0][0]);                             \
    i32x4 hi0_ = *(const i32x4*)((BUF) + ad[0][1]);                             \
    i32x4 lo1_ = *(const i32x4*)((BUF) + ad[1][0]);                             \
    i32x4 hi1_ = *(const i32x4*)((BUF) + ad[1][1]);                             \
    RX[0] = i32x8{lo0_.x, lo0_.y, lo0_.z, lo0_.w, hi0_.x, hi0_.y, hi0_.z, hi0_.w}; \
    RX[1] = i32x8{lo1_.x, lo1_.y, lo1_.z, lo1_.w, hi1_.x, hi1_.y, hi1_.z, hi1_.w}; \
  }while(0)

#define MFMA8(SX, BX) do{                                                       \
    _Pragma("unroll")                                                           \
    for (int mi_ = 0; mi_ < 4; ++mi_)                                           \
      SX[mi_] = __builtin_amdgcn_mfma_scale_f32_16x16x128_f8f6f4(afr[mi_][0], BX[0], fz, 0, 0, 0, 127, 0, 127); \
    _Pragma("unroll")                                                           \
    for (int mi_ = 0; mi_ < 4; ++mi_)                                           \
      SX[mi_] = __builtin_amdgcn_mfma_scale_f32_16x16x128_f8f6f4(afr[mi_][1], BX[1], SX[mi_], 0, 0, 0, 127, 0, 127); \
  }while(0)

#define EXPACC(SX, CY) do{                                                      \
    _Pragma("unroll")                                                           \
    for (int mi_ = 0; mi_ < 4; ++mi_){                                          \
      const f32x4 t_ = SX[mi_] * (CY);                                          \
      f32x4 e_;                                                                 \
      _Pragma("unroll")                                                         \
      for (int r_ = 0; r_ < 4; ++r_) e_[r_] = __builtin_amdgcn_exp2f(t_[r_]);   \
      acc[mi_] += e_;                                                           \
    }                                                                           \
  }while(0)

// Interval: tiles xa_, xb_=xa_+1, SEQUENTIAL register use (one r_/S_ set;
// v23 lesson). sched_barrier(0) between sub-steps pins tile-B's ds_reads
// AFTER tile-A's registers die. NISS = DMA issues ({xa_+4, xb_+4}); VN =
// vmcnt at interval end (waits the pair issued LAST interval).
#define PAIRSEQ(xa_, xb_, NISS, VN) do{                                         \
    const int ja_ = (xa_) + ((xa_) >= ib ? 1 : 0);                              \
    const int jb_ = (xb_) + ((xb_) >= ib ? 1 : 0);                              \
    i32x8 r_[2];                                                                \
    f32x4 S_[4];                                                                \
    RD(r_, dbase + (((xa_) & 7) << 12));                                        \
    const float cA_ = cscw[ja_ * 16 + lm];                                      \
    if ((NISS) >= 1) issue((xa_) + 4);                                          \
    if ((NISS) >= 2) issue((xb_) + 4);                                          \
    MFMA8(S_, r_);                                                              \
    EXPACC(S_, cA_);                                                            \
    __builtin_amdgcn_sched_barrier(0);                                          \
    RD(r_, dbase + (((xb_) & 7) << 12));                                        \
    const float cB_ = cscw[jb_ * 16 + lm];                                      \
    MFMA8(S_, r_);                                                              \
    EXPACC(S_, cB_);                                                            \
    asm volatile("s_waitcnt vmcnt(" #VN ")" ::: "memory");                      \
    __builtin_amdgcn_s_barrier();                                               \
    __builtin_amdgcn_sched_barrier(0);                                          \
  }while(0)

  // Intervals k=0..12: tiles (2k,2k+1); issue (2k+4,2k+5); vmcnt(2) waits
  // the pair issued last interval -- exactly what interval k+1 reads.
  #pragma unroll 1
  for (int k = 0; k < 13; ++k)
    PAIRSEQ(2 * k, 2 * k + 1, 2, 2);
  // k=13: tiles (26,27); issue 30 only; vmcnt(1) waits (28,29).
  PAIRSEQ(26, 27, 1, 1);
  // k=14: tiles (28,29); no issue; vmcnt(0) waits 30.
  PAIRSEQ(28, 29, 0, 0);
  // Final single tile 30 (data landed; barrier passed).
  {
    const int j30 = 30 + (30 >= ib ? 1 : 0);
    i32x8 r_[2];
    f32x4 S_[4];
    RD(r_, dbase + ((30 & 7) << 12));
    const float c_ = cscw[j30 * 16 + lm];
    MFMA8(S_, r_);
    EXPACC(S_, c_);
  }

#undef PAIRSEQ
#undef EXPACC
#undef MFMA8
#undef RD

  // Epilogue: per-dir log1p into LDS (aliases staging -- dead now), combine
  // dirs, coalesced store. C/D layout: col = lane&15, row = (lane>>4)*4+reg.
  __syncthreads();
  float* ebuf = (float*)smem;
  #pragma unroll
  for (int mi = 0; mi < 4; ++mi){
    #pragma unroll
    for (int r = 0; r < 4; ++r){
      const int m = sub * 64 + mi * 16 + (kh << 2) + r;
      ebuf[(dir * 256 + m) * 20 + lm] = __logf(1.f + acc[mi][r]);
    }
  }
  __syncthreads();
  #pragma unroll
  for (int p = 0; p < 2; ++p){
    const int i   = tid + p * 512;     // 0..1023 (float4 units of the 256x16 tile)
    const int row = i >> 2;
    const int c4  = i & 3;
    const f32x4 e0 = *(const f32x4*)(&ebuf[row * 20 + c4 * 4]);
    const f32x4 e1 = *(const f32x4*)(&ebuf[(256 + row) * 20 + c4 * 4]);
    f32x4 o;
    #pragma unroll
    for (int e = 0; e < 4; ++e) o[e] = -(e0[e] + e1[e]);
    *(f32x4*)(&out[(size_t)(r0 + row) * 256 + s0 + c4 * 4]) = o;
  }
}

extern "C" void kernel_launch(void* const* d_in, const int* in_sizes, int n_in,
                              void* d_out, int out_size, void* d_ws, size_t ws_size,
                              hipStream_t stream){
  const float* V = (const float*)d_in[2];   // back_VF  (pre_VF/pre_AF unused by reference)
  const float* A = (const float*)d_in[3];   // back_AF
  float* out = (float*)d_out;
  float* ivn = (float*)((char*)d_ws + IVN_OFF);
  float* icn = (float*)((char*)d_ws + ICN_OFF);
  float* csq = (float*)((char*)d_ws + CSQ_OFF);
  unsigned char* mats = (unsigned char*)((char*)d_ws + MATS_OFF);

  cast_ns_k<<<dim3(8, 32, 2), 256, 0, stream>>>(V, A, mats, csq);
  nreduce_k<<<dim3(32, 2), 256, 0, stream>>>(csq, ivn, icn);
  gemm_both_k<<<dim3(16, 32), 512, 0, stream>>>(mats, ivn, icn, out);
}

// Round 12
// 117.323 us; speedup vs baseline: 1.3146x; 1.0096x over previous
//
#include <hip/hip_runtime.h>
#include <cstdint>

// Problem constants: B=32, T=D=256, rows R = B*T = 8192, K = 256.
#define R_TOT 8192
#define KD    256
#define SLOT  ((size_t)R_TOT * KD)            // bytes per fp8 image (2,097,152)
// ws layout (bytes):  total ~4.8 MB
#define IVN_OFF  0                            // 64 f32: 1/frobenius-norm [ten][j]
#define ICN_OFF  256                          // 2*8192 f32: 1/col-norm [ten][j][s]
#define CSQ_OFF  (ICN_OFF + 65536)            // 8 tc-partials x 2*8192 f32 = 512 KB
#define MATS_OFF (CSQ_OFF + 524288)           // 2 fp8 images (Vq, Aq), swizzled, 4 MB

typedef float f32x4 __attribute__((ext_vector_type(4)));
typedef int   i32x4 __attribute__((ext_vector_type(4)));
typedef int   i32x8 __attribute__((ext_vector_type(8)));   // 32 fp8 = one MX MFMA operand

__device__ __forceinline__ void glds16(const void* g, void* l){
  __builtin_amdgcn_global_load_lds((const __attribute__((address_space(1))) uint32_t*)g,
                                   (__attribute__((address_space(3))) uint32_t*)l, 16, 0, 0);
}

// Image layout (R11-verbatim): plain k-order rows (256 B per image row r), 16B
// chunk c (k in [c*16, c*16+16)) stored at 16B slot c ^ (r & 15). XOR swizzle
// keeps MFMA-layout ds_read_b128 conflict-free (verified R7-R11).
__global__ void cast_ns_k(const float* __restrict__ V, const float* __restrict__ A,
                          unsigned char* __restrict__ mats, float* __restrict__ csq){
  const int tc = blockIdx.x, j = blockIdx.y, ten = blockIdx.z;
  const int tid = threadIdx.x;
  const int g    = tid & 31;                 // d-chunk of 8 floats = 8 fp8 bytes
  const int tsub = tid >> 5;                 // 0..7
  const int c    = g >> 1;                   // 16B chunk index 0..15
  const int half = g & 1;                    // which 8B half of the chunk
  const float* X = (ten ? A : V) + (size_t)j * 65536;
  unsigned char* M = mats + (size_t)ten * SLOT + (size_t)j * 65536;
  float cs[8];
  #pragma unroll
  for (int e = 0; e < 8; ++e) cs[e] = 0.f;
  #pragma unroll
  for (int tt = 0; tt < 4; ++tt){
    const int t = tc * 32 + tt * 8 + tsub;
    const float4 p0 = *(const float4*)(X + t * 256 + g * 8);
    const float4 p1 = *(const float4*)(X + t * 256 + g * 8 + 4);
    cs[0] += p0.x * p0.x; cs[1] += p0.y * p0.y; cs[2] += p0.z * p0.z; cs[3] += p0.w * p0.w;
    cs[4] += p1.x * p1.x; cs[5] += p1.y * p1.y; cs[6] += p1.z * p1.z; cs[7] += p1.w * p1.w;
    int d0 = __builtin_amdgcn_cvt_pk_fp8_f32(p0.x, p0.y, 0, false);
    d0     = __builtin_amdgcn_cvt_pk_fp8_f32(p0.z, p0.w, d0, true);
    int d1 = __builtin_amdgcn_cvt_pk_fp8_f32(p1.x, p1.y, 0, false);
    d1     = __builtin_amdgcn_cvt_pk_fp8_f32(p1.z, p1.w, d1, true);
    int2 o; o.x = d0; o.y = d1;
    *(int2*)(M + (size_t)t * 256 + (((c ^ (t & 15)) << 4) | (half << 3))) = o;
  }
  __shared__ float red[8][256];
  #pragma unroll
  for (int e = 0; e < 8; ++e) red[tsub][g * 8 + e] = cs[e];
  __syncthreads();
  float s = 0.f;
  #pragma unroll
  for (int gg = 0; gg < 8; ++gg) s += red[gg][tid];
  csq[(size_t)((tc * 2 + ten) * 32 + j) * 256 + tid] = s;
}

// Finish norms: sum 8 tc-partials; icn = rsqrt, ivn = rsqrt of row-sum. Grid (32, 2).
__global__ void nreduce_k(const float* __restrict__ csq, float* __restrict__ ivn,
                          float* __restrict__ icn){
  const int j = blockIdx.x, ten = blockIdx.y, s = threadIdx.x;
  float c = 0.f;
  #pragma unroll
  for (int tc = 0; tc < 8; ++tc)
    c += csq[(size_t)((tc * 2 + ten) * 32 + j) * 256 + s];
  icn[ten * 8192 + j * 256 + s] = rsqrtf(c + 1e-18f);
  __shared__ float red[256];
  red[s] = c; __syncthreads();
  for (int off = 128; off > 0; off >>= 1){
    if (s < off) red[s] += red[s + off];
    __syncthreads();
  }
  if (s == 0) ivn[ten * 32 + j] = rsqrtf(red[0] + 1e-18f);
}

// v25 = v22 per-tile code + FREE-RUNNING 4-tile windows (barrier every 4
// tiles, 8 total, NO fences inside the window).
// Unified series model: private-staging variants (v13/16/17/19) were bound
// by the ~10.5-11.3 TB/s glds service ceiling (508 MB -> 45-48us, schedule-
// invariant). v22 cut staging to 127 MB (11.5us, not binding) but its
// per-tile s_barrier locksteps the block: step time = ONE wave's serial
// chain (lgkm ~120 + MFMA ~276 + exp/trans ~256 + addr ~ 800 cy), pipes
// idle at 28%/40%. v24's fences re-serialized within pairs (null). v25
// gives the compiler a fence-free 4-tile window: tile t's exp chain can
// overlap tile t+1's ds_read/MFMA -- cross-tile pipelining the per-tile
// barrier forbade. DMA: 8-deep bufs; at window start issue the NEXT
// window's 4 tiles (disjoint buffer half; WAR covered by prev barrier);
// vmcnt(0) at window end is ~free (DMAs aged a full ~1300cy window).
// Per-tile code is byte-identical to v22 (proven clean at (512,4) budget
// 128). SPILL DETECTOR: WRITE_SIZE (clean = 8MB; ballooned -> (512,3)).
__global__ __launch_bounds__(512, 4) void gemm_both_k(const unsigned char* __restrict__ mats,
                                                      const float* __restrict__ ivn,
                                                      const float* __restrict__ icn,
                                                      float* __restrict__ out){
  // [0,64K): 2 dirs x 8 bufs x 4KB staging; [64K,68K): csc[2][32][16] f32.
  // Epilogue ebuf f32[2][256][20] = 40960 B aliases the staging (post-loop).
  __shared__ __align__(16) char smem[69632];
  const int tid  = threadIdx.x;
  const int lane = tid & 63;
  const int w    = tid >> 6;            // 0..7
  const int dir  = w >> 2;              // waves 0-3 -> dir0; 4-7 -> dir1
  const int sub  = w & 3;               // row-64-group AND staging-chunk index
  const int lm   = lane & 15;
  const int kh   = lane >> 4;           // 0..3 (k-quad per K-half)
  const int s0   = blockIdx.x * 16;     // 16-col tile
  const int rb   = blockIdx.y;          // row-block == batch index i
  const int r0   = rb * 256;
  const int ib   = rb;                  // excluded diagonal j == i

  // dir0: rows Vq (scale 1/|V_i|F), cols Aq (scale 1/colnorm A); dir1 swapped.
  const unsigned char* rowmat = mats + (size_t)dir * SLOT;
  const unsigned char* colmat = mats + (size_t)(1 - dir) * SLOT;
  const float sivn = ivn[dir * 32 + ib] * 1.44269504088896340736f;  // * log2(e)

  char*  dbase = smem + dir * 32768;                  // this dir's 8 x 4KB bufs
  float* cscw  = (float*)(smem + 65536) + dir * 512;  // this dir's csc[32][16]
  const unsigned char* colbase = colmat + (size_t)s0 * 256;  // 4KB j-tile @ +j*65536
  const int lo16 = lane * 16;

  // Stage this wave's 1KB chunk of the dir's 4KB tile for col-tile x.
  auto issue = [&](int x){
    const int j = x + (x >= ib ? 1 : 0);
    glds16(colbase + (size_t)j * 65536 + sub * 1024 + lo16,
           dbase + ((x & 7) << 12) + sub * 1024 + lo16);
  };

  issue(0); issue(1); issue(2); issue(3);

  // Block-shared csc table (per dir): csc[j][col] = sivn * icn_col[j*256+s0+col].
  {
    const float* ib2 = icn + (size_t)(1 - dir) * 8192 + s0 + lm;
    #pragma unroll
    for (int jx = 0; jx < 2; ++jx){
      const int j = sub * 8 + jx * 4 + kh;
      cscw[j * 16 + lm] = sivn * ib2[j * 256];
    }
  }

  // A-fragments: this wave's 64 rows (group sub of the 256-row block);
  // K-half t, 16B unit u at slot (t*8 + kh*2 + u) ^ lm. 64 regs, invariant.
  i32x8 afr[4][2];                      // [mi][K-half]
  #pragma unroll
  for (int mi = 0; mi < 4; ++mi){
    const unsigned char* rp = rowmat + (size_t)(r0 + sub * 64 + mi * 16 + lm) * 256;
    #pragma unroll
    for (int t = 0; t < 2; ++t){
      i32x4 lo = *(const i32x4*)(rp + ((((t << 3) | (kh << 1) | 0) ^ lm) << 4));
      i32x4 hi = *(const i32x4*)(rp + ((((t << 3) | (kh << 1) | 1) ^ lm) << 4));
      afr[mi][t] = i32x8{lo.x, lo.y, lo.z, lo.w, hi.x, hi.y, hi.z, hi.w};
    }
  }
  #pragma unroll
  for (int mi = 0; mi < 4; ++mi)
    #pragma unroll
    for (int t = 0; t < 2; ++t)
      asm volatile("" : "+v"(afr[mi][t]));

  // ds_read offsets: tile row lm, K-half t, unit u; (row&15)==lm so the XOR
  // key matches staging (s0 multiple of 16).
  int ad[2][2];                         // [K-half][unit]
  #pragma unroll
  for (int t = 0; t < 2; ++t)
    #pragma unroll
    for (int u = 0; u < 2; ++u)
      ad[t][u] = lm * 256 + ((((t << 3) | (kh << 1) | u) ^ lm) << 4);

  f32x4 acc[4];
  #pragma unroll
  for (int mi = 0; mi < 4; ++mi)
    acc[mi] = f32x4{0.f, 0.f, 0.f, 0.f};
  const f32x4 fz = {0.f, 0.f, 0.f, 0.f};   // hoisted zero C-operand for MFMA t=0

  // Drain prologue (csc gloads + afr + DMA(0..3) + csc LDS writes), sync.
  asm volatile("s_waitcnt vmcnt(0) lgkmcnt(0)" ::: "memory");
  __builtin_amdgcn_s_barrier();
  __builtin_amdgcn_sched_barrier(0);

// One j-tile, v22-verbatim: ds_read b128 x4 -> MFMA x8 -> mul/exp/acc.
// No fences: the compiler pipelines adjacent tiles within a window.
#define TILE(x_) do{                                                            \
    const int j_ = (x_) + ((x_) >= ib ? 1 : 0);                                 \
    const char* rbuf_ = dbase + (((x_) & 7) << 12);                             \
    i32x8 b_[2];                                                                \
    {                                                                           \
      i32x4 lo0 = *(const i32x4*)(rbuf_ + ad[0][0]);                            \
      i32x4 hi0 = *(const i32x4*)(rbuf_ + ad[0][1]);                            \
      i32x4 lo1 = *(const i32x4*)(rbuf_ + ad[1][0]);                            \
      i32x4 hi1 = *(const i32x4*)(rbuf_ + ad[1][1]);                            \
      b_[0] = i32x8{lo0.x, lo0.y, lo0.z, lo0.w, hi0.x, hi0.y, hi0.z, hi0.w};    \
      b_[1] = i32x8{lo1.x, lo1.y, lo1.z, lo1.w, hi1.x, hi1.y, hi1.z, hi1.w};    \
    }                                                                           \
    const float csc_ = cscw[j_ * 16 + lm];                                      \
    f32x4 S_[4];                                                                \
    _Pragma("unroll")                                                           \
    for (int mi_ = 0; mi_ < 4; ++mi_)                                           \
      S_[mi_] = __builtin_amdgcn_mfma_scale_f32_16x16x128_f8f6f4(afr[mi_][0], b_[0], fz, 0, 0, 0, 127, 0, 127); \
    _Pragma("unroll")                                                           \
    for (int mi_ = 0; mi_ < 4; ++mi_)                                           \
      S_[mi_] = __builtin_amdgcn_mfma_scale_f32_16x16x128_f8f6f4(afr[mi_][1], b_[1], S_[mi_], 0, 0, 0, 127, 0, 127); \
    _Pragma("unroll")                                                           \
    for (int mi_ = 0; mi_ < 4; ++mi_){                                          \
      const f32x4 t_ = S_[mi_] * csc_;                                          \
      f32x4 e_;                                                                 \
      _Pragma("unroll")                                                         \
      for (int r_ = 0; r_ < 4; ++r_) e_[r_] = __builtin_amdgcn_exp2f(t_[r_]);   \
      acc[mi_] += e_;                                                           \
    }                                                                           \
  }while(0)

  // 7 full windows of 4 tiles (0..27), then a 3-tile tail (28..30).
  // Window wnd: reads tiles base..base+3 (landed, confirmed by the previous
  // vmcnt(0)+barrier); issues tiles base+4..base+7 (into the OTHER buffer
  // half -- WAR covered by the previous barrier); vmcnt(0)+barrier at end.
  #pragma unroll 1
  for (int wnd = 0; wnd < 7; ++wnd){
    const int base = wnd * 4;
    issue(base + 4);
    issue(base + 5);
    if (base + 6 <= 30) issue(base + 6);
    if (base + 7 <= 30) issue(base + 7);
    TILE(base + 0);
    TILE(base + 1);
    TILE(base + 2);
    TILE(base + 3);
    asm volatile("s_waitcnt vmcnt(0)" ::: "memory");
    __builtin_amdgcn_s_barrier();
    __builtin_amdgcn_sched_barrier(0);
  }
  TILE(28);
  TILE(29);
  TILE(30);

#undef TILE

  // Epilogue: per-dir log1p into LDS (aliases staging -- dead now), combine
  // dirs, coalesced store. C/D layout: col = lane&15, row = (lane>>4)*4+reg.
  __syncthreads();
  float* ebuf = (float*)smem;
  #pragma unroll
  for (int mi = 0; mi < 4; ++mi){
    #pragma unroll
    for (int r = 0; r < 4; ++r){
      const int m = sub * 64 + mi * 16 + (kh << 2) + r;
      ebuf[(dir * 256 + m) * 20 + lm] = __logf(1.f + acc[mi][r]);
    }
  }
  __syncthreads();
  #pragma unroll
  for (int p = 0; p < 2; ++p){
    const int i   = tid + p * 512;     // 0..1023 (float4 units of the 256x16 tile)
    const int row = i >> 2;
    const int c4  = i & 3;
    const f32x4 e0 = *(const f32x4*)(&ebuf[row * 20 + c4 * 4]);
    const f32x4 e1 = *(const f32x4*)(&ebuf[(256 + row) * 20 + c4 * 4]);
    f32x4 o;
    #pragma unroll
    for (int e = 0; e < 4; ++e) o[e] = -(e0[e] + e1[e]);
    *(f32x4*)(&out[(size_t)(r0 + row) * 256 + s0 + c4 * 4]) = o;
  }
}

extern "C" void kernel_launch(void* const* d_in, const int* in_sizes, int n_in,
                              void* d_out, int out_size, void* d_ws, size_t ws_size,
                              hipStream_t stream){
  const float* V = (const float*)d_in[2];   // back_VF  (pre_VF/pre_AF unused by reference)
  const float* A = (const float*)d_in[3];   // back_AF
  float* out = (float*)d_out;
  float* ivn = (float*)((char*)d_ws + IVN_OFF);
  float* icn = (float*)((char*)d_ws + ICN_OFF);
  float* csq = (float*)((char*)d_ws + CSQ_OFF);
  unsigned char* mats = (unsigned char*)((char*)d_ws + MATS_OFF);

  cast_ns_k<<<dim3(8, 32, 2), 256, 0, stream>>>(V, A, mats, csq);
  nreduce_k<<<dim3(32, 2), 256, 0, stream>>>(csq, ivn, icn);
  gemm_both_k<<<dim3(16, 32), 512, 0, stream>>>(mats, ivn, icn, out);
}

// Round 13
// 115.685 us; speedup vs baseline: 1.3332x; 1.0142x over previous
//
#include <hip/hip_runtime.h>
#include <cstdint>

// Problem constants: B=32, T=D=256, rows R = B*T = 8192, K = 256.
#define R_TOT 8192
#define KD    256
#define SLOT  ((size_t)R_TOT * KD)            // bytes per fp8 image (2,097,152)
// ws layout (bytes):  total ~4.8 MB
#define IVN_OFF  0                            // 64 f32: 1/frobenius-norm [ten][j]
#define ICN_OFF  256                          // 2*8192 f32: 1/col-norm [ten][j][s]
#define CSQ_OFF  (ICN_OFF + 65536)            // 8 tc-partials x 2*8192 f32 = 512 KB
#define MATS_OFF (CSQ_OFF + 524288)           // 2 fp8 images (Vq, Aq), swizzled, 4 MB

typedef float f32x4 __attribute__((ext_vector_type(4)));
typedef int   i32x4 __attribute__((ext_vector_type(4)));
typedef int   i32x8 __attribute__((ext_vector_type(8)));   // 32 fp8 = one MX MFMA operand

__device__ __forceinline__ void glds16(const void* g, void* l){
  __builtin_amdgcn_global_load_lds((const __attribute__((address_space(1))) uint32_t*)g,
                                   (__attribute__((address_space(3))) uint32_t*)l, 16, 0, 0);
}

// Image layout (R11-verbatim): plain k-order rows (256 B per image row r), 16B
// chunk c (k in [c*16, c*16+16)) stored at 16B slot c ^ (r & 15). XOR swizzle
// keeps MFMA-layout ds_read_b128 conflict-free (verified R7-R11).
__global__ void cast_ns_k(const float* __restrict__ V, const float* __restrict__ A,
                          unsigned char* __restrict__ mats, float* __restrict__ csq){
  const int tc = blockIdx.x, j = blockIdx.y, ten = blockIdx.z;
  const int tid = threadIdx.x;
  const int g    = tid & 31;                 // d-chunk of 8 floats = 8 fp8 bytes
  const int tsub = tid >> 5;                 // 0..7
  const int c    = g >> 1;                   // 16B chunk index 0..15
  const int half = g & 1;                    // which 8B half of the chunk
  const float* X = (ten ? A : V) + (size_t)j * 65536;
  unsigned char* M = mats + (size_t)ten * SLOT + (size_t)j * 65536;
  float cs[8];
  #pragma unroll
  for (int e = 0; e < 8; ++e) cs[e] = 0.f;
  #pragma unroll
  for (int tt = 0; tt < 4; ++tt){
    const int t = tc * 32 + tt * 8 + tsub;
    const float4 p0 = *(const float4*)(X + t * 256 + g * 8);
    const float4 p1 = *(const float4*)(X + t * 256 + g * 8 + 4);
    cs[0] += p0.x * p0.x; cs[1] += p0.y * p0.y; cs[2] += p0.z * p0.z; cs[3] += p0.w * p0.w;
    cs[4] += p1.x * p1.x; cs[5] += p1.y * p1.y; cs[6] += p1.z * p1.z; cs[7] += p1.w * p1.w;
    int d0 = __builtin_amdgcn_cvt_pk_fp8_f32(p0.x, p0.y, 0, false);
    d0     = __builtin_amdgcn_cvt_pk_fp8_f32(p0.z, p0.w, d0, true);
    int d1 = __builtin_amdgcn_cvt_pk_fp8_f32(p1.x, p1.y, 0, false);
    d1     = __builtin_amdgcn_cvt_pk_fp8_f32(p1.z, p1.w, d1, true);
    int2 o; o.x = d0; o.y = d1;
    *(int2*)(M + (size_t)t * 256 + (((c ^ (t & 15)) << 4) | (half << 3))) = o;
  }
  __shared__ float red[8][256];
  #pragma unroll
  for (int e = 0; e < 8; ++e) red[tsub][g * 8 + e] = cs[e];
  __syncthreads();
  float s = 0.f;
  #pragma unroll
  for (int gg = 0; gg < 8; ++gg) s += red[gg][tid];
  csq[(size_t)((tc * 2 + ten) * 32 + j) * 256 + tid] = s;
}

// Finish norms: sum 8 tc-partials; icn = rsqrt, ivn = rsqrt of row-sum. Grid (32, 2).
__global__ void nreduce_k(const float* __restrict__ csq, float* __restrict__ ivn,
                          float* __restrict__ icn){
  const int j = blockIdx.x, ten = blockIdx.y, s = threadIdx.x;
  float c = 0.f;
  #pragma unroll
  for (int tc = 0; tc < 8; ++tc)
    c += csq[(size_t)((tc * 2 + ten) * 32 + j) * 256 + s];
  icn[ten * 8192 + j * 256 + s] = rsqrtf(c + 1e-18f);
  __shared__ float red[256];
  red[s] = c; __syncthreads();
  for (int off = 128; off > 0; off >>= 1){
    if (s < off) red[s] += red[s + off];
    __syncthreads();
  }
  if (s == 0) ivn[ten * 32 + j] = rsqrtf(red[0] + 1e-18f);
}

// v26 = v25 with the window-end drain FIXED. v25 issued next-window DMAs at
// window start but then waited vmcnt(0) at window end -- draining the
// just-issued DMAs = the m97 stall at window granularity (measured: v25 ~=
// v22, null). v26: 2-tile windows, DMA issued THREE windows ahead (8-deep
// buffers), end-of-window wait = vmcnt(4): leaves the 4 newest DMAs in
// flight ACROSS the barrier; waits only the pair issued 2 windows (~1700cy)
// ago >= DMA latency -> wait ~free. 16 barriers (vs v22's 31), zero
// mid-loop drains, no fences inside windows, per-tile code byte-identical
// to v22 (proven 128-reg clean at (512,4)).
// Invariant: at window-w start, outstanding = tiles {2w+2..2w+5}. Issue
// {2w+6,2w+7} -> 6. End vmcnt(4) completes {2w+2,2w+3} = exactly window
// w+1's reads. Tail: w=12 issues t30, vmcnt(3); w=13 vmcnt(1); w=14
// vmcnt(0); then TILE(30). WAR: buf x&7, reader finished 4 windows before
// re-write, barrier-separated. SPILL DETECTOR: WRITE_SIZE (clean = 8MB).
__global__ __launch_bounds__(512, 4) void gemm_both_k(const unsigned char* __restrict__ mats,
                                                      const float* __restrict__ ivn,
                                                      const float* __restrict__ icn,
                                                      float* __restrict__ out){
  // [0,64K): 2 dirs x 8 bufs x 4KB staging; [64K,68K): csc[2][32][16] f32.
  // Epilogue ebuf f32[2][256][20] = 40960 B aliases the staging (post-loop).
  __shared__ __align__(16) char smem[69632];
  const int tid  = threadIdx.x;
  const int lane = tid & 63;
  const int w    = tid >> 6;            // 0..7
  const int dir  = w >> 2;              // waves 0-3 -> dir0; 4-7 -> dir1
  const int sub  = w & 3;               // row-64-group AND staging-chunk index
  const int lm   = lane & 15;
  const int kh   = lane >> 4;           // 0..3 (k-quad per K-half)
  const int s0   = blockIdx.x * 16;     // 16-col tile
  const int rb   = blockIdx.y;          // row-block == batch index i
  const int r0   = rb * 256;
  const int ib   = rb;                  // excluded diagonal j == i

  // dir0: rows Vq (scale 1/|V_i|F), cols Aq (scale 1/colnorm A); dir1 swapped.
  const unsigned char* rowmat = mats + (size_t)dir * SLOT;
  const unsigned char* colmat = mats + (size_t)(1 - dir) * SLOT;
  const float sivn = ivn[dir * 32 + ib] * 1.44269504088896340736f;  // * log2(e)

  char*  dbase = smem + dir * 32768;                  // this dir's 8 x 4KB bufs
  float* cscw  = (float*)(smem + 65536) + dir * 512;  // this dir's csc[32][16]
  const unsigned char* colbase = colmat + (size_t)s0 * 256;  // 4KB j-tile @ +j*65536
  const int lo16 = lane * 16;

  // Stage this wave's 1KB chunk of the dir's 4KB tile for col-tile x.
  auto issue = [&](int x){
    const int j = x + (x >= ib ? 1 : 0);
    glds16(colbase + (size_t)j * 65536 + sub * 1024 + lo16,
           dbase + ((x & 7) << 12) + sub * 1024 + lo16);
  };

  issue(0); issue(1);

  // Block-shared csc table (per dir): csc[j][col] = sivn * icn_col[j*256+s0+col].
  {
    const float* ib2 = icn + (size_t)(1 - dir) * 8192 + s0 + lm;
    #pragma unroll
    for (int jx = 0; jx < 2; ++jx){
      const int j = sub * 8 + jx * 4 + kh;
      cscw[j * 16 + lm] = sivn * ib2[j * 256];
    }
  }

  // A-fragments: this wave's 64 rows (group sub of the 256-row block);
  // K-half t, 16B unit u at slot (t*8 + kh*2 + u) ^ lm. 64 regs, invariant.
  i32x8 afr[4][2];                      // [mi][K-half]
  #pragma unroll
  for (int mi = 0; mi < 4; ++mi){
    const unsigned char* rp = rowmat + (size_t)(r0 + sub * 64 + mi * 16 + lm) * 256;
    #pragma unroll
    for (int t = 0; t < 2; ++t){
      i32x4 lo = *(const i32x4*)(rp + ((((t << 3) | (kh << 1) | 0) ^ lm) << 4));
      i32x4 hi = *(const i32x4*)(rp + ((((t << 3) | (kh << 1) | 1) ^ lm) << 4));
      afr[mi][t] = i32x8{lo.x, lo.y, lo.z, lo.w, hi.x, hi.y, hi.z, hi.w};
    }
  }
  #pragma unroll
  for (int mi = 0; mi < 4; ++mi)
    #pragma unroll
    for (int t = 0; t < 2; ++t)
      asm volatile("" : "+v"(afr[mi][t]));

  issue(2); issue(3); issue(4); issue(5);

  // ds_read offsets: tile row lm, K-half t, unit u; (row&15)==lm so the XOR
  // key matches staging (s0 multiple of 16).
  int ad[2][2];                         // [K-half][unit]
  #pragma unroll
  for (int t = 0; t < 2; ++t)
    #pragma unroll
    for (int u = 0; u < 2; ++u)
      ad[t][u] = lm * 256 + ((((t << 3) | (kh << 1) | u) ^ lm) << 4);

  f32x4 acc[4];
  #pragma unroll
  for (int mi = 0; mi < 4; ++mi)
    acc[mi] = f32x4{0.f, 0.f, 0.f, 0.f};
  const f32x4 fz = {0.f, 0.f, 0.f, 0.f};   // hoisted zero C-operand for MFMA t=0

  // Prologue wait: queue = {t0,t1, csc(2), afr(16), t2..t5}. vmcnt(4) leaves
  // the 4 newest (t2..t5) in flight; t0,t1 + csc + afr complete. lgkmcnt(0)
  // covers the csc LDS writes. Barrier publishes csc + staged chunks.
  asm volatile("s_waitcnt vmcnt(4) lgkmcnt(0)" ::: "memory");
  __builtin_amdgcn_s_barrier();
  __builtin_amdgcn_sched_barrier(0);

// One j-tile, v22-verbatim: ds_read b128 x4 -> MFMA x8 -> mul/exp/acc.
// No fences inside a window: compiler may pipeline the two tiles.
#define TILE(x_) do{                                                            \
    const int j_ = (x_) + ((x_) >= ib ? 1 : 0);                                 \
    const char* rbuf_ = dbase + (((x_) & 7) << 12);                             \
    i32x8 b_[2];                                                                \
    {                                                                           \
      i32x4 lo0 = *(const i32x4*)(rbuf_ + ad[0][0]);                            \
      i32x4 hi0 = *(const i32x4*)(rbuf_ + ad[0][1]);                            \
      i32x4 lo1 = *(const i32x4*)(rbuf_ + ad[1][0]);                            \
      i32x4 hi1 = *(const i32x4*)(rbuf_ + ad[1][1]);                            \
      b_[0] = i32x8{lo0.x, lo0.y, lo0.z, lo0.w, hi0.x, hi0.y, hi0.z, hi0.w};    \
      b_[1] = i32x8{lo1.x, lo1.y, lo1.z, lo1.w, hi1.x, hi1.y, hi1.z, hi1.w};    \
    }                                                                           \
    const float csc_ = cscw[j_ * 16 + lm];                                      \
    f32x4 S_[4];                                                                \
    _Pragma("unroll")                                                           \
    for (int mi_ = 0; mi_ < 4; ++mi_)                                           \
      S_[mi_] = __builtin_amdgcn_mfma_scale_f32_16x16x128_f8f6f4(afr[mi_][0], b_[0], fz, 0, 0, 0, 127, 0, 127); \
    _Pragma("unroll")                                                           \
    for (int mi_ = 0; mi_ < 4; ++mi_)                                           \
      S_[mi_] = __builtin_amdgcn_mfma_scale_f32_16x16x128_f8f6f4(afr[mi_][1], b_[1], S_[mi_], 0, 0, 0, 127, 0, 127); \
    _Pragma("unroll")                                                           \
    for (int mi_ = 0; mi_ < 4; ++mi_){                                          \
      const f32x4 t_ = S_[mi_] * csc_;                                          \
      f32x4 e_;                                                                 \
      _Pragma("unroll")                                                         \
      for (int r_ = 0; r_ < 4; ++r_) e_[r_] = __builtin_amdgcn_exp2f(t_[r_]);   \
      acc[mi_] += e_;                                                           \
    }                                                                           \
  }while(0)

  // Windows w=0..11: tiles (2w,2w+1); issue (2w+6,2w+7); end vmcnt(4) ->
  // {2w+2,2w+3} landed (next window's reads), 4 newest stay in flight.
  #pragma unroll 1
  for (int wd = 0; wd < 12; ++wd){
    issue(2 * wd + 6);
    issue(2 * wd + 7);
    TILE(2 * wd);
    TILE(2 * wd + 1);
    asm volatile("s_waitcnt vmcnt(4)" ::: "memory");
    __builtin_amdgcn_s_barrier();
    __builtin_amdgcn_sched_barrier(0);
  }
  // w=12: tiles (24,25); issue t30; outstanding {26..30}; vmcnt(3) -> 26,27.
  issue(30);
  TILE(24);
  TILE(25);
  asm volatile("s_waitcnt vmcnt(3)" ::: "memory");
  __builtin_amdgcn_s_barrier();
  __builtin_amdgcn_sched_barrier(0);
  // w=13: tiles (26,27); vmcnt(1) -> 28,29 landed (t30 in flight).
  TILE(26);
  TILE(27);
  asm volatile("s_waitcnt vmcnt(1)" ::: "memory");
  __builtin_amdgcn_s_barrier();
  __builtin_amdgcn_sched_barrier(0);
  // w=14: tiles (28,29); vmcnt(0) -> t30 landed.
  TILE(28);
  TILE(29);
  asm volatile("s_waitcnt vmcnt(0)" ::: "memory");
  __builtin_amdgcn_s_barrier();
  __builtin_amdgcn_sched_barrier(0);
  TILE(30);

#undef TILE

  // Epilogue: per-dir log1p into LDS (aliases staging -- dead now), combine
  // dirs, coalesced store. C/D layout: col = lane&15, row = (lane>>4)*4+reg.
  __syncthreads();
  float* ebuf = (float*)smem;
  #pragma unroll
  for (int mi = 0; mi < 4; ++mi){
    #pragma unroll
    for (int r = 0; r < 4; ++r){
      const int m = sub * 64 + mi * 16 + (kh << 2) + r;
      ebuf[(dir * 256 + m) * 20 + lm] = __logf(1.f + acc[mi][r]);
    }
  }
  __syncthreads();
  #pragma unroll
  for (int p = 0; p < 2; ++p){
    const int i   = tid + p * 512;     // 0..1023 (float4 units of the 256x16 tile)
    const int row = i >> 2;
    const int c4  = i & 3;
    const f32x4 e0 = *(const f32x4*)(&ebuf[row * 20 + c4 * 4]);
    const f32x4 e1 = *(const f32x4*)(&ebuf[(256 + row) * 20 + c4 * 4]);
    f32x4 o;
    #pragma unroll
    for (int e = 0; e < 4; ++e) o[e] = -(e0[e] + e1[e]);
    *(f32x4*)(&out[(size_t)(r0 + row) * 256 + s0 + c4 * 4]) = o;
  }
}

extern "C" void kernel_launch(void* const* d_in, const int* in_sizes, int n_in,
                              void* d_out, int out_size, void* d_ws, size_t ws_size,
                              hipStream_t stream){
  const float* V = (const float*)d_in[2];   // back_VF  (pre_VF/pre_AF unused by reference)
  const float* A = (const float*)d_in[3];   // back_AF
  float* out = (float*)d_out;
  float* ivn = (float*)((char*)d_ws + IVN_OFF);
  float* icn = (float*)((char*)d_ws + ICN_OFF);
  float* csq = (float*)((char*)d_ws + CSQ_OFF);
  unsigned char* mats = (unsigned char*)((char*)d_ws + MATS_OFF);

  cast_ns_k<<<dim3(8, 32, 2), 256, 0, stream>>>(V, A, mats, csq);
  nreduce_k<<<dim3(32, 2), 256, 0, stream>>>(csq, ivn, icn);
  gemm_both_k<<<dim3(16, 32), 512, 0, stream>>>(mats, ivn, icn, out);
}